// Round 1
// baseline (51.646 us; speedup 1.0000x reference)
//
#include <hip/hip_runtime.h>

// IIR filter bank: B=16 seqs of T=32768, F=30 filters, order 6 (K=7).
// Parallelization: overlap-and-discard chunking. Poles have |p| <= 0.95,
// so 512 warm-up samples make the zero-state start exact to ~4e-12.
// Each thread: one (b, f, chunk) triple; runs DF2T recursion over
// [max(0, t0-WARM), t0+CHUNK), stores the last CHUNK samples.

#define BB 16
#define TT 32768
#define FF 30
#define KK 7
#define ORD 6
#define CHUNK 256
#define WARM 512
#define NCHUNK (TT / CHUNK)  // 128

// Transposed direct-form II step: 13 FMAs, no state shifting.
//   y    = b0*x + s1
//   s_j  = b_j*x + s_{j+1} - a_j*y   (s_{ORD+1} = 0)
__device__ __forceinline__ float iir_step(float xv, float st[ORD],
                                          const float bc[KK],
                                          const float ac[ORD]) {
    float y = fmaf(bc[0], xv, st[0]);
#pragma unroll
    for (int j = 0; j < ORD - 1; ++j)
        st[j] = fmaf(-ac[j], y, fmaf(bc[j + 1], xv, st[j + 1]));
    st[ORD - 1] = fmaf(-ac[ORD - 1], y, bc[KK - 1] * xv);
    return y;
}

__global__ __launch_bounds__(256) void iir_chunked_kernel(
    const float* __restrict__ x,    // [B][T]
    const float* __restrict__ bs,   // [F][K]
    const float* __restrict__ as_,  // [F][K]
    float* __restrict__ out)        // [B][F][T]
{
    const int tid = blockIdx.x * blockDim.x + threadIdx.x;
    // f fastest: lanes in a wave mostly share (b, chunk) -> broadcast x loads
    const int f = tid % FF;
    const int rest = tid / FF;
    const int chunk = rest % NCHUNK;
    const int b = rest / NCHUNK;

    // Load + normalize coefficients (reference divides by a0; a0 == 1 here
    // from np.poly, but normalize anyway for exact parity).
    const float inv_a0 = 1.0f / as_[f * KK];
    float bc[KK], ac[ORD];
#pragma unroll
    for (int j = 0; j < KK; ++j) bc[j] = bs[f * KK + j] * inv_a0;
#pragma unroll
    for (int j = 0; j < ORD; ++j) ac[j] = as_[f * KK + 1 + j] * inv_a0;

    const float* __restrict__ xrow = x + b * TT;
    const int t0 = chunk * CHUNK;
    int ws = t0 - WARM;
    if (ws < 0) ws = 0;  // chunks 0..2: exact zero-state start at t=0

    float st[ORD];
#pragma unroll
    for (int j = 0; j < ORD; ++j) st[j] = 0.0f;

    // Warm-up: run recursion, discard outputs. ws and t0 are multiples of
    // 256 -> float4 loads are 16B-aligned and trip count is a multiple of 4.
    for (int t = ws; t < t0; t += 4) {
        const float4 xv = *reinterpret_cast<const float4*>(xrow + t);
        (void)iir_step(xv.x, st, bc, ac);
        (void)iir_step(xv.y, st, bc, ac);
        (void)iir_step(xv.z, st, bc, ac);
        (void)iir_step(xv.w, st, bc, ac);
    }

    // Output phase: keep outputs, store float4 every 4 steps.
    float* __restrict__ orow = out + (b * FF + f) * TT;
    for (int t = t0; t < t0 + CHUNK; t += 4) {
        const float4 xv = *reinterpret_cast<const float4*>(xrow + t);
        float4 yv;
        yv.x = iir_step(xv.x, st, bc, ac);
        yv.y = iir_step(xv.y, st, bc, ac);
        yv.z = iir_step(xv.z, st, bc, ac);
        yv.w = iir_step(xv.w, st, bc, ac);
        *reinterpret_cast<float4*>(orow + t) = yv;
    }
}

extern "C" void kernel_launch(void* const* d_in, const int* in_sizes, int n_in,
                              void* d_out, int out_size, void* d_ws,
                              size_t ws_size, hipStream_t stream) {
    const float* x   = (const float*)d_in[0];
    const float* bs  = (const float*)d_in[1];
    const float* as_ = (const float*)d_in[2];
    float* out = (float*)d_out;

    const int total = BB * FF * NCHUNK;  // 61440
    const int block = 256;
    const int grid = total / block;      // 240
    hipLaunchKernelGGL(iir_chunked_kernel, dim3(grid), dim3(block), 0, stream,
                       x, bs, as_, out);
}